// Round 1
// baseline (62.809 us; speedup 1.0000x reference)
//
#include <hip/hip_runtime.h>
#include <hip/hip_bf16.h>

#define MULC 128
#define IN_DIM 1152
#define ROWS_PER_WG 64
#define NTHREADS 256

typedef __attribute__((ext_vector_type(8))) short bf16x8;
typedef __attribute__((ext_vector_type(4))) float f32x4;
typedef __attribute__((ext_vector_type(4))) unsigned short u16x4;

// LDS layout (ushort units):
//  W1T: [v=0..127][pitch 136]  -> offset 0,      size 128*136 = 17408
//  A:   [c=0..2][r=0..63][pitch 40] -> offset 17408, plane 2560, size 7680
// total 25088 ushorts = 50176 B
#define W1T_PITCH 136
#define A_BASE 17408
#define A_PITCH 40
#define A_PLANE 2560

__device__ __forceinline__ unsigned short f2bf(float f) {
    unsigned int b = __builtin_bit_cast(unsigned int, f);
    b += 0x7fffu + ((b >> 16) & 1u);   // round-to-nearest-even
    return (unsigned short)(b >> 16);
}

__global__ __launch_bounds__(NTHREADS, 2)
void nltp_kernel(const float* __restrict__ x, const float* __restrict__ W1,
                 const float* __restrict__ W2, const float* __restrict__ tpw,
                 float* __restrict__ out)
{
    __shared__ __align__(16) unsigned short lds[25088];
    const int t  = threadIdx.x;
    const int n0 = blockIdx.x * ROWS_PER_WG;
    const int l  = t & 63;
    const int w  = t >> 6;      // wave 0..3, owns rows [16w, 16w+16)
    const int g  = l >> 4;      // 4-lane-group id 0..3
    const int li = l & 15;

    // ---- stage W1^T as bf16, padded pitch (once per WG) ----
    for (int it = 0; it < 16; ++it) {
        int tau = it * 256 + t;
        int v   = tau & 127;
        int u   = (tau >> 7) * 4;          // 0,4,...,124
        float f0 = W1[(u + 0) * MULC + v];
        float f1 = W1[(u + 1) * MULC + v];
        float f2 = W1[(u + 2) * MULC + v];
        float f3 = W1[(u + 3) * MULC + v];
        u16x4 pk = { f2bf(f0), f2bf(f1), f2bf(f2), f2bf(f3) };
        *(u16x4*)&lds[v * W1T_PITCH + u] = pk;
    }

    f32x4 acc[3][8];
#pragma unroll
    for (int c = 0; c < 3; ++c)
#pragma unroll
        for (int nt = 0; nt < 8; ++nt)
            acc[c][nt] = (f32x4){0.f, 0.f, 0.f, 0.f};

    // ---- K loop: 4 chunks of 32 u's, single-buffered LDS A tile ----
    for (int kc = 0; kc < 4; ++kc) {
        __syncthreads();   // also covers W1T staging on kc==0
#pragma unroll
        for (int q = 0; q < 2; ++q) {
            int idx = q * 256 + t;         // 0..511
            int r   = idx >> 3;            // row in tile 0..63
            int j   = idx & 7;             // 12-float chunk within row
            const float* src = x + (size_t)(n0 + r) * IN_DIM + MULC + kc * 96 + j * 12;
            float4 v0 = *(const float4*)(src);
            float4 v1 = *(const float4*)(src + 4);
            float4 v2 = *(const float4*)(src + 8);
            // elements e_i, i=0..11 -> u_local = 4j + i/3, c = i%3
            u16x4 p0 = { f2bf(v0.x), f2bf(v0.w), f2bf(v1.z), f2bf(v2.y) };
            u16x4 p1 = { f2bf(v0.y), f2bf(v1.x), f2bf(v1.w), f2bf(v2.z) };
            u16x4 p2 = { f2bf(v0.z), f2bf(v1.y), f2bf(v2.x), f2bf(v2.w) };
            int base = A_BASE + r * A_PITCH + 4 * j;
            *(u16x4*)&lds[base]              = p0;
            *(u16x4*)&lds[base + A_PLANE]    = p1;
            *(u16x4*)&lds[base + 2 * A_PLANE] = p2;
        }
        __syncthreads();

        bf16x8 af[3];
#pragma unroll
        for (int c = 0; c < 3; ++c)
            af[c] = *(const bf16x8*)&lds[A_BASE + c * A_PLANE + (16 * w + li) * A_PITCH + g * 8];
#pragma unroll
        for (int nt = 0; nt < 8; ++nt) {
            bf16x8 bf = *(const bf16x8*)&lds[(nt * 16 + li) * W1T_PITCH + kc * 32 + g * 8];
#pragma unroll
            for (int c = 0; c < 3; ++c)
                acc[c][nt] = __builtin_amdgcn_mfma_f32_16x16x32_bf16(af[c], bf, acc[c][nt], 0, 0, 0);
        }
    }

    // ---- epilogue: silu + W2 contraction + 16-lane reduce + TP readout ----
    const float inv = 0.08838834764831845f;  // 1/sqrt(128)
    float w2a[8], w2b[8];
#pragma unroll
    for (int nt = 0; nt < 8; ++nt) {
        float2 p = *(const float2*)(W2 + 2 * (nt * 16 + li));
        w2a[nt] = p.x; w2b[nt] = p.y;
    }
    float pa[3][4], pb[3][4];
#pragma unroll
    for (int c = 0; c < 3; ++c)
#pragma unroll
        for (int rg = 0; rg < 4; ++rg) { pa[c][rg] = 0.f; pb[c][rg] = 0.f; }

#pragma unroll
    for (int c = 0; c < 3; ++c)
#pragma unroll
        for (int nt = 0; nt < 8; ++nt)
#pragma unroll
            for (int rg = 0; rg < 4; ++rg) {
                float y = acc[c][nt][rg] * inv;
                float s = y / (1.f + __expf(-y));   // silu
                pa[c][rg] += s * w2a[nt];
                pb[c][rg] += s * w2b[nt];
            }

#pragma unroll
    for (int c = 0; c < 3; ++c)
#pragma unroll
        for (int rg = 0; rg < 4; ++rg) {
            float va = pa[c][rg], vb = pb[c][rg];
            va += __shfl_xor(va, 1, 16); vb += __shfl_xor(vb, 1, 16);
            va += __shfl_xor(va, 2, 16); vb += __shfl_xor(vb, 2, 16);
            va += __shfl_xor(va, 4, 16); vb += __shfl_xor(vb, 4, 16);
            va += __shfl_xor(va, 8, 16); vb += __shfl_xor(vb, 8, 16);
            pa[c][rg] = va * inv;
            pb[c][rg] = vb * inv;
        }

    const float tw0 = tpw[0], tw1 = tpw[1], tw2 = tpw[2];
    const float k0 = tw0 * 0.5773502691896258f;   // 1/sqrt(3)
    const float k1 = tw1 * 0.7071067811865476f;   // sqrt(3)/sqrt(6)
    const float s2 = 0.7071067811865476f;
    const float s6 = 0.4082482904638631f;         // 1/sqrt(6)

#pragma unroll
    for (int rg = 0; rg < 4; ++rg) {
        float a0 = pa[0][rg], a1 = pa[1][rg], a2 = pa[2][rg];
        float b0 = pb[0][rg], b1 = pb[1][rg], b2 = pb[2][rg];
        float o0 = k0 * (a0 * b0 + a1 * b1 + a2 * b2);
        float o1 = k1 * (a1 * b2 - a2 * b1);
        float o2 = k1 * (a2 * b0 - a0 * b2);
        float o3 = k1 * (a0 * b1 - a1 * b0);
        float o4 = tw2 * (s2 * (a2 * b0 + a0 * b2));
        float o5 = tw2 * (s2 * (a0 * b1 + a1 * b0));
        float o6 = tw2 * (s6 * (2.f * a1 * b1 - a2 * b2 - a0 * b0));
        float o7 = tw2 * (s2 * (a2 * b1 + a1 * b2));
        float o8 = tw2 * (s2 * (a2 * b2 - a0 * b0));
        float o = li == 0 ? o0 : li == 1 ? o1 : li == 2 ? o2 : li == 3 ? o3 :
                  li == 4 ? o4 : li == 5 ? o5 : li == 6 ? o6 : li == 7 ? o7 : o8;
        if (li < 9) {
            int row = n0 + 16 * w + 4 * g + rg;
            out[row * 9 + li] = o;
        }
    }
}

extern "C" void kernel_launch(void* const* d_in, const int* in_sizes, int n_in,
                              void* d_out, int out_size, void* d_ws, size_t ws_size,
                              hipStream_t stream) {
    const float* x   = (const float*)d_in[0];
    const float* W1  = (const float*)d_in[1];
    const float* W2  = (const float*)d_in[2];
    const float* tpw = (const float*)d_in[3];
    float* out = (float*)d_out;
    const int n = in_sizes[0] / IN_DIM;           // 131072
    dim3 grid(n / ROWS_PER_WG);                   // 2048
    nltp_kernel<<<grid, NTHREADS, 0, stream>>>(x, W1, W2, tpw, out);
}